// Round 1
// baseline (1016.115 us; speedup 1.0000x reference)
//
#include <hip/hip_runtime.h>
#include <hip/hip_bf16.h>
#include <math.h>

#define NROW 8
#define DT   2097152   // D = D1*D2
#define DD1  2048
#define DD2  1024
#define BATCH 512

// ws layout:
//  [0)                         vsum  : NROW*DT floats (67,108,864 B)
//  [67108864)                  code  : DT bytes (2,097,152 B)
//  [69206016)                  meta  : u32[1412]
//    meta[0] beta_key, [1] alpha_key, [2] gmax2_bits, [3] gmax3_bits
//    [4..132)   counts level2   [132..260) counts level3
//    [260..388) final_rank(int) [388..1284) msp_tab (float 128*7)
//    [1284..1412) scheme bits (u32, bit i = rs_i)

__device__ __forceinline__ unsigned fenc(float f){
  unsigned u = __float_as_uint(f);
  return (u & 0x80000000u) ? ~u : (u | 0x80000000u);
}
__device__ __forceinline__ float fdec(unsigned k){
  return (k & 0x80000000u) ? __uint_as_float(k ^ 0x80000000u) : __uint_as_float(~k);
}
__device__ __forceinline__ float sigmoid_ref(float z){
  #pragma clang fp contract(off)
  return 1.0f / (1.0f + expf(-z));
}

// ---- 8-element sorting networks (Batcher odd-even, 19 comparators) ----
#define CSWAPV(a,b) { float _lo=fminf(a,b), _hi=fmaxf(a,b); a=_lo; b=_hi; }
__device__ __forceinline__ void sort8v(float v[8]){
  CSWAPV(v[0],v[1]) CSWAPV(v[2],v[3]) CSWAPV(v[4],v[5]) CSWAPV(v[6],v[7])
  CSWAPV(v[0],v[2]) CSWAPV(v[1],v[3]) CSWAPV(v[4],v[6]) CSWAPV(v[5],v[7])
  CSWAPV(v[1],v[2]) CSWAPV(v[5],v[6])
  CSWAPV(v[0],v[4]) CSWAPV(v[1],v[5]) CSWAPV(v[2],v[6]) CSWAPV(v[3],v[7])
  CSWAPV(v[2],v[4]) CSWAPV(v[3],v[5])
  CSWAPV(v[1],v[2]) CSWAPV(v[3],v[4]) CSWAPV(v[5],v[6])
}
__device__ __forceinline__ void cswapkv(float&av,int&ai,float&bv,int&bi){
  bool sw = (av > bv) || ((av == bv) && (ai > bi));   // lexicographic -> stable sort
  float nav = sw ? bv : av; float nbv = sw ? av : bv;
  int   nai = sw ? bi : ai; int   nbi = sw ? ai : bi;
  av = nav; bv = nbv; ai = nai; bi = nbi;
}
#define CSWAPK(i,j) cswapkv(v[i],ix[i],v[j],ix[j]);
__device__ __forceinline__ void sort8kv(float v[8], int ix[8]){
  CSWAPK(0,1) CSWAPK(2,3) CSWAPK(4,5) CSWAPK(6,7)
  CSWAPK(0,2) CSWAPK(1,3) CSWAPK(4,6) CSWAPK(5,7)
  CSWAPK(1,2) CSWAPK(5,6)
  CSWAPK(0,4) CSWAPK(1,5) CSWAPK(2,6) CSWAPK(3,7)
  CSWAPK(2,4) CSWAPK(3,5)
  CSWAPK(1,2) CSWAPK(3,4) CSWAPK(5,6)
}

// residual loader: LEVEL==2 recomputes level-1 vsum from U; LEVEL==3 reads vsum
template<int LEVEL>
__device__ __forceinline__ void load_res(const float* __restrict__ U, const float* __restrict__ vsum,
                                         int d, float s1, float res[8], float base[8]){
  #pragma clang fp contract(off)
  #pragma unroll
  for (int i = 0; i < 8; ++i){
    size_t off = (size_t)i*DT + d;
    float u = U[off];
    float b;
    if (LEVEL == 2) b = s1 * floorf(u / s1);
    else            b = vsum[off];
    base[i] = b;
    res[i]  = u - b;
  }
}

__global__ void k_init(unsigned* __restrict__ meta){
  int t = threadIdx.x;
  if (t == 0){ meta[0] = 0u; meta[1] = 0xFFFFFFFFu; meta[2] = 0u; meta[3] = 0u; }
  if (t < 128){ meta[4+t] = 0u; meta[132+t] = 0u; }
}

__global__ __launch_bounds__(256) void k_minmax(const float* __restrict__ U, unsigned* __restrict__ meta){
  __shared__ unsigned smx[256], smn[256];
  int t = threadIdx.x;
  size_t i = (size_t)blockIdx.x*256 + t;
  size_t stride = (size_t)gridDim.x*256;
  float mx = -INFINITY, mn = INFINITY;
  for (; i < (size_t)NROW*DT; i += stride){ float v = U[i]; mx = fmaxf(mx,v); mn = fminf(mn,v); }
  smx[t] = fenc(mx); smn[t] = fenc(mn);
  __syncthreads();
  for (int o = 128; o > 0; o >>= 1){
    if (t < o){ smx[t] = max(smx[t], smx[t+o]); smn[t] = min(smn[t], smn[t+o]); }
    __syncthreads();
  }
  if (t == 0){ atomicMax(&meta[0], smx[0]); atomicMin(&meta[1], smn[0]); }
}

template<int LEVEL>
__global__ __launch_bounds__(256) void k_passA(const float* __restrict__ U, const float* __restrict__ vsum,
                                               unsigned* __restrict__ meta){
  #pragma clang fp contract(off)
  __shared__ unsigned sred[256];
  int t = threadIdx.x;
  int d = blockIdx.x*256 + t;
  float beta = fdec(meta[0]), alpha = fdec(meta[1]);
  float s1 = (beta - alpha) / 3.0f;
  float res[8], base[8];
  load_res<LEVEL>(U, vsum, d, s1, res, base);
  sort8v(res);
  float m = 0.0f;
  #pragma unroll
  for (int i = 0; i < 7; ++i) m = fmaxf(m, res[i+1] - res[i]);
  sred[t] = __float_as_uint(m);           // deltas >= 0 -> bits are order-preserving
  __syncthreads();
  for (int o = 128; o > 0; o >>= 1){
    if (t < o) sred[t] = max(sred[t], sred[t+o]);
    __syncthreads();
  }
  if (t == 0) atomicMax(&meta[(LEVEL==2)?2:3], sred[0]);
}

template<int LEVEL>
__global__ __launch_bounds__(256) void k_passB(const float* __restrict__ U, const float* __restrict__ vsum,
                                               const float* __restrict__ thres_mean,
                                               unsigned char* __restrict__ code, unsigned* __restrict__ meta){
  #pragma clang fp contract(off)
  __shared__ int hist[128];
  int t = threadIdx.x;
  if (t < 128) hist[t] = 0;
  __syncthreads();
  int d = blockIdx.x*256 + t;
  float beta = fdec(meta[0]), alpha = fdec(meta[1]);
  float s1 = (beta - alpha) / 3.0f;
  float gmax = __uint_as_float(meta[(LEVEL==2)?2:3]);
  float res[8], base[8];
  load_res<LEVEL>(U, vsum, d, s1, res, base);
  sort8v(res);
  float tm = thres_mean[d >> 11];         // thr[d] = sigmoid(thres_mean[d / D1])
  float thr = sigmoid_ref(tm);
  int c = 0;
  #pragma unroll
  for (int i = 0; i < 7; ++i){
    float dn  = (res[i+1] - res[i]) / gmax;
    float z   = (dn - thr) / 0.01f;
    float msp = sigmoid_ref(z);
    int bit = (int)rintf(msp);            // half-to-even like jnp.round
    c = (c << 1) | bit;                   // MSB-first: weight 2^(6-i)
  }
  code[d] = (unsigned char)c;
  atomicAdd(&hist[c], 1);
  __syncthreads();
  if (t < 128 && hist[t] > 0) atomicAdd((int*)&meta[((LEVEL==2)?4:132) + t], hist[t]);
}

template<int LEVEL>
__global__ void k_small(const float* __restrict__ U, const float* __restrict__ vsum,
                        const float* __restrict__ thres_mean, unsigned* __restrict__ meta){
  #pragma clang fp contract(off)
  __shared__ int cs[128], rk[128];
  __shared__ int top_code[5], top_rank[5];
  int c = threadIdx.x;                    // 128 threads
  cs[c] = (int)meta[((LEVEL==2)?4:132) + c];
  __syncthreads();
  int r = 0;
  for (int j = 0; j < c; ++j) r += (cs[j] > 0) ? 1 : 0;   // rank_of_code (exclusive presence scan)
  rk[c] = r;
  __syncthreads();
  if (c == 0){
    int tmp[128];
    for (int j = 0; j < 128; ++j) tmp[j] = cs[j];
    for (int k = 0; k < 5; ++k){          // stable argsort(-counts)[:5]: max count, ties -> lowest idx
      int best = 0, bc = tmp[0];
      for (int j = 1; j < 128; ++j){ if (tmp[j] > bc){ bc = tmp[j]; best = j; } }
      top_code[k] = best; top_rank[k] = rk[best]; tmp[best] = -1;
    }
  }
  __syncthreads();
  int besti = -1, sel = 0;
  #pragma unroll
  for (int j = 0; j < 5; ++j){            // argmax first-wins over shared-bit counts
    int inter = __popc(c & top_code[j]);
    if (inter > besti){ besti = inter; sel = j; }
  }
  bool is_top = false;
  #pragma unroll
  for (int j = 0; j < 5; ++j) is_top = is_top || (rk[c] == top_rank[j]);
  int fr = is_top ? rk[c] : top_rank[sel];
  ((int*)meta)[260 + c] = fr;
  // msp/scheme table for columns 0..127 (the only ones c_rank can address)
  float beta = fdec(meta[0]), alpha = fdec(meta[1]);
  float s1 = (beta - alpha) / 3.0f;
  float gmax = __uint_as_float(meta[(LEVEL==2)?2:3]);
  float res[8], base[8];
  load_res<LEVEL>(U, vsum, c, s1, res, base);
  sort8v(res);
  float tm = thres_mean[c >> 11];
  float thr = sigmoid_ref(tm);
  unsigned bits = 0;
  float* msp_tab = (float*)&meta[388];
  #pragma unroll
  for (int i = 0; i < 7; ++i){
    float dn  = (res[i+1] - res[i]) / gmax;
    float z   = (dn - thr) / 0.01f;
    float msp = sigmoid_ref(z);
    msp_tab[c*7 + i] = msp;
    bits |= ((unsigned)(int)rintf(msp)) << i;
  }
  meta[1284 + c] = bits;
}

template<int LEVEL>
__global__ __launch_bounds__(256) void k_passD(const float* __restrict__ U, float* __restrict__ vsum,
                                               const unsigned char* __restrict__ code,
                                               unsigned* __restrict__ meta){
  #pragma clang fp contract(off)
  __shared__ int fr_s[128];
  __shared__ unsigned bits_s[128];
  __shared__ float msp_s[128*7];
  int t = threadIdx.x;
  if (t < 128){ fr_s[t] = ((int*)meta)[260 + t]; bits_s[t] = meta[1284 + t]; }
  for (int i = t; i < 128*7; i += 256) msp_s[i] = ((float*)&meta[388])[i];
  __syncthreads();
  int d = blockIdx.x*256 + t;
  float beta = fdec(meta[0]), alpha = fdec(meta[1]);
  float s1 = (beta - alpha) / 3.0f;
  float s2 = s1 / 5.0f;
  float s  = (LEVEL == 2) ? s2 : (s2 / 17.0f);
  float v[8], base[8]; int ix[8];
  load_res<LEVEL>(U, vsum, d, s1, v, base);
  #pragma unroll
  for (int i = 0; i < 8; ++i) ix[i] = i;
  sort8kv(v, ix);                          // stable: reproduces jnp.argsort
  int cr = fr_s[code[d]];
  unsigned sb = bits_s[cr];
  // segmented mean scan (exact op order of the reference)
  float vv[8]; bool bl[8];
  float buf = 0.0f, cnt = 0.0f, g = 1.0f; bool reset = false;
  #pragma unroll
  for (int i = 0; i < 8; ++i){
    buf = reset ? v[i] : (buf + v[i]);
    cnt = reset ? 1.0f : (cnt + 1.0f);
    g   = reset ? 1.0f : g;
    float m = buf / cnt;
    if (i == 7){ vv[7] = g * m; bl[7] = true; }
    else {
      float msp = msp_s[cr*7 + i];
      bool b = ((sb >> i) & 1u) != 0u;
      vv[i] = b ? ((g * msp) * m) : 0.0f;
      bl[i] = b;
      g = b ? g : (g * (1.0f - msp));
      reset = b;
    }
  }
  float out = vv[7];
  float inner[8];
  inner[7] = out;
  for (int i = 6; i >= 0; --i){ if (bl[i]) out = vv[i]; inner[i] = out; }
  #pragma unroll
  for (int i = 0; i < 8; ++i){
    float q = s * floorf(inner[i] / s);
    int orig = ix[i];
    vsum[(size_t)orig*DT + d] = base[orig] + q;
  }
}

// ---- fp32 SIMT GEMM: out[b,n,l] = sum_k x[b,n,k] * w[n,k,l]; 64x64 tile, 4x4/thread
__global__ __launch_bounds__(256) void k_gemm(const float* __restrict__ x, const float* __restrict__ w,
                                              float* __restrict__ out){
  __shared__ __align__(16) float As[32][68];  // As[k][m], pad 68 -> aligned + conflict-free
  __shared__ __align__(16) float Bs[32][68];  // Bs[k][l]
  int t  = threadIdx.x;
  int tx = t & 15, ty = t >> 4;
  int n  = blockIdx.z;
  int m0 = blockIdx.y * 64;
  int l0 = blockIdx.x * 64;
  const float* Ag = x + ((size_t)m0*NROW + n)*DD1;   // row stride between b's: 8*2048
  const float* Bg = w + (size_t)n*DT + l0;           // w[n][k][l] = vsum[n*DT + k*1024 + l]
  float acc[4][4] = {};
  for (int k0 = 0; k0 < DD1; k0 += 32){
    #pragma unroll
    for (int i = 0; i < 2; ++i){
      int id = t + i*256;                 // 64 rows x 8 float4
      int row = id >> 3, kc = (id & 7) * 4;
      float4 a = *(const float4*)(Ag + (size_t)row*(NROW*DD1) + k0 + kc);
      As[kc+0][row] = a.x; As[kc+1][row] = a.y; As[kc+2][row] = a.z; As[kc+3][row] = a.w;
    }
    #pragma unroll
    for (int i = 0; i < 2; ++i){
      int id = t + i*256;                 // 32 k-rows x 16 float4
      int kr = id >> 4, lc = (id & 15) * 4;
      float4 b = *(const float4*)(Bg + (size_t)(k0 + kr)*DD2 + lc);
      *(float4*)&Bs[kr][lc] = b;
    }
    __syncthreads();
    #pragma unroll
    for (int kk = 0; kk < 32; ++kk){
      float4 a4 = *(const float4*)&As[kk][ty*4];
      float4 b4 = *(const float4*)&Bs[kk][tx*4];
      float av[4] = {a4.x, a4.y, a4.z, a4.w};
      float bv[4] = {b4.x, b4.y, b4.z, b4.w};
      #pragma unroll
      for (int i = 0; i < 4; ++i)
        #pragma unroll
        for (int j = 0; j < 4; ++j)
          acc[i][j] = fmaf(av[i], bv[j], acc[i][j]);
    }
    __syncthreads();
  }
  #pragma unroll
  for (int i = 0; i < 4; ++i){
    float4 o; o.x = acc[i][0]; o.y = acc[i][1]; o.z = acc[i][2]; o.w = acc[i][3];
    *(float4*)(out + ((size_t)(m0 + ty*4 + i)*NROW + n)*DD2 + l0 + tx*4) = o;
  }
}

extern "C" void kernel_launch(void* const* d_in, const int* in_sizes, int n_in,
                              void* d_out, int out_size, void* d_ws, size_t ws_size,
                              hipStream_t stream){
  const float* x  = (const float*)d_in[0];
  const float* U  = (const float*)d_in[1];
  const float* tm = (const float*)d_in[2];
  float* out  = (float*)d_out;
  float* vsum = (float*)d_ws;
  unsigned char* code = (unsigned char*)d_ws + (size_t)NROW*DT*4;
  unsigned* meta = (unsigned*)((unsigned char*)d_ws + (size_t)NROW*DT*4 + DT);
  (void)in_sizes; (void)n_in; (void)out_size; (void)ws_size;

  int nb = DT / 256;  // 8192 blocks, one thread per column

  k_init  <<<1,    256, 0, stream>>>(meta);
  k_minmax<<<2048, 256, 0, stream>>>(U, meta);

  // level 2 (deno = 5)
  k_passA<2><<<nb, 256, 0, stream>>>(U, vsum, meta);
  k_passB<2><<<nb, 256, 0, stream>>>(U, vsum, tm, code, meta);
  k_small<2><<<1,  128, 0, stream>>>(U, vsum, tm, meta);
  k_passD<2><<<nb, 256, 0, stream>>>(U, vsum, code, meta);

  // level 3 (deno = 17)
  k_passA<3><<<nb, 256, 0, stream>>>(U, vsum, meta);
  k_passB<3><<<nb, 256, 0, stream>>>(U, vsum, tm, code, meta);
  k_small<3><<<1,  128, 0, stream>>>(U, vsum, tm, meta);
  k_passD<3><<<nb, 256, 0, stream>>>(U, vsum, code, meta);

  // epilogue: out = x @ w per slice n
  k_gemm<<<dim3(DD2/64, BATCH/64, NROW), 256, 0, stream>>>(x, vsum, out);
}

// Round 2
// 477.013 us; speedup vs baseline: 2.1302x; 2.1302x over previous
//
#include <hip/hip_runtime.h>
#include <hip/hip_bf16.h>
#include <math.h>

#define NROW 8
#define DT   2097152   // D = D1*D2
#define DD1  2048
#define DD2  1024
#define BATCH 512
#define NBLK 2048      // grid-stride blocks for quant passes
#define NCH  4         // chunks per block (NBLK*256*NCH == DT)

// ws layout:
//  [0)           vsum : NROW*DT floats            (67,108,864 B)
//  [67108864)    code : DT bytes                  ( 2,097,152 B)
//  [69206016)    wt   : NROW*DT bf16 [n][l][k]    (33,554,432 B)
//  [102760448)   meta : u32[1412]
//    meta[0] beta_key, [1] alpha_key, [2] gmax2_bits, [3] gmax3_bits
//    [4..132) counts lvl2  [132..260) counts lvl3
//    [260..388) final_rank  [388..1284) msp_tab (float 128*7)
//    [1284..1412) scheme bits (u32, bit i = rs_i)

typedef __attribute__((ext_vector_type(8))) short short8;
typedef __attribute__((ext_vector_type(4))) float f32x4;

__device__ __forceinline__ unsigned fenc(float f){
  unsigned u = __float_as_uint(f);
  return (u & 0x80000000u) ? ~u : (u | 0x80000000u);
}
__device__ __forceinline__ float fdec(unsigned k){
  return (k & 0x80000000u) ? __uint_as_float(k ^ 0x80000000u) : __uint_as_float(~k);
}
__device__ __forceinline__ float sigmoid_ref(float z){
  #pragma clang fp contract(off)
  return 1.0f / (1.0f + expf(-z));
}
__device__ __forceinline__ unsigned short f2bf(float f){
  __hip_bfloat16 h = __float2bfloat16(f);
  return *reinterpret_cast<unsigned short*>(&h);
}

// ---- 8-element sorting networks (Batcher odd-even, 19 comparators) ----
#define CSWAPV(a,b) { float _lo=fminf(a,b), _hi=fmaxf(a,b); a=_lo; b=_hi; }
__device__ __forceinline__ void sort8v(float v[8]){
  CSWAPV(v[0],v[1]) CSWAPV(v[2],v[3]) CSWAPV(v[4],v[5]) CSWAPV(v[6],v[7])
  CSWAPV(v[0],v[2]) CSWAPV(v[1],v[3]) CSWAPV(v[4],v[6]) CSWAPV(v[5],v[7])
  CSWAPV(v[1],v[2]) CSWAPV(v[5],v[6])
  CSWAPV(v[0],v[4]) CSWAPV(v[1],v[5]) CSWAPV(v[2],v[6]) CSWAPV(v[3],v[7])
  CSWAPV(v[2],v[4]) CSWAPV(v[3],v[5])
  CSWAPV(v[1],v[2]) CSWAPV(v[3],v[4]) CSWAPV(v[5],v[6])
}
__device__ __forceinline__ void cswapkv(float&av,int&ai,float&bv,int&bi){
  bool sw = (av > bv) || ((av == bv) && (ai > bi));   // lexicographic -> stable sort
  float nav = sw ? bv : av; float nbv = sw ? av : bv;
  int   nai = sw ? bi : ai; int   nbi = sw ? ai : bi;
  av = nav; bv = nbv; ai = nai; bi = nbi;
}
#define CSWAPK(i,j) cswapkv(v[i],ix[i],v[j],ix[j]);
__device__ __forceinline__ void sort8kv(float v[8], int ix[8]){
  CSWAPK(0,1) CSWAPK(2,3) CSWAPK(4,5) CSWAPK(6,7)
  CSWAPK(0,2) CSWAPK(1,3) CSWAPK(4,6) CSWAPK(5,7)
  CSWAPK(1,2) CSWAPK(5,6)
  CSWAPK(0,4) CSWAPK(1,5) CSWAPK(2,6) CSWAPK(3,7)
  CSWAPK(2,4) CSWAPK(3,5)
  CSWAPK(1,2) CSWAPK(3,4) CSWAPK(5,6)
}

__global__ void k_init(unsigned* __restrict__ meta){
  int t = threadIdx.x;
  if (t == 0){ meta[0] = 0u; meta[1] = 0xFFFFFFFFu; meta[2] = 0u; meta[3] = 0u; }
  if (t < 128){ meta[4+t] = 0u; meta[132+t] = 0u; }
}

__global__ __launch_bounds__(256) void k_minmax(const float* __restrict__ U, unsigned* __restrict__ meta){
  __shared__ unsigned smx[256], smn[256];
  int t = threadIdx.x;
  size_t i = (size_t)blockIdx.x*256 + t;
  size_t stride = (size_t)gridDim.x*256;
  float mx = -INFINITY, mn = INFINITY;
  for (; i < (size_t)NROW*DT; i += stride){ float v = U[i]; mx = fmaxf(mx,v); mn = fminf(mn,v); }
  smx[t] = fenc(mx); smn[t] = fenc(mn);
  __syncthreads();
  for (int o = 128; o > 0; o >>= 1){
    if (t < o){ smx[t] = max(smx[t], smx[t+o]); smn[t] = min(smn[t], smn[t+o]); }
    __syncthreads();
  }
  if (t == 0){ atomicMax(&meta[0], smx[0]); atomicMin(&meta[1], smn[0]); }
}

// level-2 only: max sorted-residual delta (res from recomputed level-1 vsum)
__global__ __launch_bounds__(256) void k_passA2(const float* __restrict__ U, unsigned* __restrict__ meta){
  #pragma clang fp contract(off)
  __shared__ unsigned sred[256];
  int t = threadIdx.x;
  float beta = fdec(meta[0]), alpha = fdec(meta[1]);
  float s1 = (beta - alpha) / 3.0f;
  unsigned dmax = 0u;
  for (int ch = 0; ch < NCH; ++ch){
    int d = (blockIdx.x + ch*NBLK)*256 + t;
    float res[8];
    #pragma unroll
    for (int i = 0; i < 8; ++i){
      float u = U[(size_t)i*DT + d];
      res[i] = u - s1*floorf(u/s1);
    }
    sort8v(res);
    float m = 0.0f;
    #pragma unroll
    for (int i = 0; i < 7; ++i) m = fmaxf(m, res[i+1] - res[i]);
    dmax = max(dmax, __float_as_uint(m));   // deltas >= 0: bits order-preserving
  }
  sred[t] = dmax;
  __syncthreads();
  for (int o = 128; o > 0; o >>= 1){
    if (t < o) sred[t] = max(sred[t], sred[t+o]);
    __syncthreads();
  }
  if (t == 0) atomicMax(&meta[2], sred[0]);
}

template<int LEVEL>
__global__ __launch_bounds__(256) void k_passB(const float* __restrict__ U, const float* __restrict__ vsum,
                                               const float* __restrict__ thres_mean,
                                               unsigned char* __restrict__ code, unsigned* __restrict__ meta){
  #pragma clang fp contract(off)
  __shared__ int hist[128];
  int t = threadIdx.x;
  if (t < 128) hist[t] = 0;
  __syncthreads();
  float beta = fdec(meta[0]), alpha = fdec(meta[1]);
  float s1 = (beta - alpha) / 3.0f;
  float gmax = __uint_as_float(meta[(LEVEL==2)?2:3]);
  for (int ch = 0; ch < NCH; ++ch){
    int d = (blockIdx.x + ch*NBLK)*256 + t;
    float res[8];
    #pragma unroll
    for (int i = 0; i < 8; ++i){
      size_t off = (size_t)i*DT + d;
      float u = U[off];
      float b = (LEVEL==2) ? s1*floorf(u/s1) : vsum[off];
      res[i] = u - b;
    }
    sort8v(res);
    float thr = sigmoid_ref(thres_mean[d >> 11]);   // thr[d] = sigmoid(thres_mean[d / D1])
    int c = 0;
    #pragma unroll
    for (int i = 0; i < 7; ++i){
      float dn  = (res[i+1] - res[i]) / gmax;
      float z   = (dn - thr) / 0.01f;
      float msp = sigmoid_ref(z);
      int bit = (int)rintf(msp);                     // half-to-even like jnp.round
      c = (c << 1) | bit;                            // MSB-first
    }
    code[d] = (unsigned char)c;
    atomicAdd(&hist[c], 1);
  }
  __syncthreads();
  if (t < 128 && hist[t] > 0) atomicAdd((int*)&meta[((LEVEL==2)?4:132) + t], hist[t]);
}

template<int LEVEL>
__global__ void k_small(const float* __restrict__ U, const float* __restrict__ vsum,
                        const float* __restrict__ thres_mean, unsigned* __restrict__ meta){
  #pragma clang fp contract(off)
  __shared__ int cs[128], rk[128], redk[128];
  __shared__ int top_code[5], top_rank[5];
  __shared__ int w0cnt;
  int c = threadIdx.x;                    // 128 threads
  cs[c] = (int)meta[((LEVEL==2)?4:132) + c];
  bool present = cs[c] > 0;
  unsigned long long bm = __ballot(present);
  int lane = c & 63;
  int r = (int)__popcll(bm & ((1ull << lane) - 1ull));
  if (c == 63) w0cnt = (int)__popcll(bm);
  __syncthreads();
  if (c >= 64) r += w0cnt;
  rk[c] = r;
  __syncthreads();
  // top-5 argsort(-counts), ties -> lowest index
  for (int k = 0; k < 5; ++k){
    redk[c] = (cs[c] << 7) | (127 - c);
    __syncthreads();
    for (int o = 64; o > 0; o >>= 1){
      if (c < o) redk[c] = max(redk[c], redk[c+o]);
      __syncthreads();
    }
    if (c == 0){
      int best = 127 - (redk[0] & 127);
      top_code[k] = best; top_rank[k] = rk[best];
      cs[best] = -1;
    }
    __syncthreads();
  }
  int besti = -1, sel = 0;
  #pragma unroll
  for (int j = 0; j < 5; ++j){            // argmax first-wins over shared-bit counts
    int inter = __popc(c & top_code[j]);
    if (inter > besti){ besti = inter; sel = j; }
  }
  bool is_top = false;
  #pragma unroll
  for (int j = 0; j < 5; ++j) is_top = is_top || (rk[c] == top_rank[j]);
  int fr = is_top ? rk[c] : top_rank[sel];
  ((int*)meta)[260 + c] = fr;
  // msp/scheme table for columns 0..127 (the only ones c_rank can address)
  float beta = fdec(meta[0]), alpha = fdec(meta[1]);
  float s1 = (beta - alpha) / 3.0f;
  float gmax = __uint_as_float(meta[(LEVEL==2)?2:3]);
  float res[8];
  #pragma unroll
  for (int i = 0; i < 8; ++i){
    size_t off = (size_t)i*DT + c;
    float u = U[off];
    float b = (LEVEL==2) ? s1*floorf(u/s1) : vsum[off];
    res[i] = u - b;
  }
  sort8v(res);
  float thr = sigmoid_ref(thres_mean[c >> 11]);
  unsigned bits = 0;
  float* msp_tab = (float*)&meta[388];
  #pragma unroll
  for (int i = 0; i < 7; ++i){
    float dn  = (res[i+1] - res[i]) / gmax;
    float z   = (dn - thr) / 0.01f;
    float msp = sigmoid_ref(z);
    msp_tab[c*7 + i] = msp;
    bits |= ((unsigned)(int)rintf(msp)) << i;
  }
  meta[1284 + c] = bits;
}

// passD: apply segmented-mean quantization; LEVEL==2 fuses next level's passA
template<int LEVEL>
__global__ __launch_bounds__(256) void k_passD(const float* __restrict__ U, float* __restrict__ vsum,
                                               const unsigned char* __restrict__ code,
                                               unsigned* __restrict__ meta){
  #pragma clang fp contract(off)
  __shared__ int fr_s[128];
  __shared__ unsigned bits_s[128];
  __shared__ float msp_s[128*7];
  __shared__ unsigned sred[256];
  int t = threadIdx.x;
  if (t < 128){ fr_s[t] = ((int*)meta)[260 + t]; bits_s[t] = meta[1284 + t]; }
  for (int i = t; i < 128*7; i += 256) msp_s[i] = ((float*)&meta[388])[i];
  __syncthreads();
  float beta = fdec(meta[0]), alpha = fdec(meta[1]);
  float s1 = (beta - alpha) / 3.0f;
  float s2 = s1 / 5.0f;
  float s  = (LEVEL == 2) ? s2 : (s2 / 17.0f);
  unsigned dmax = 0u;
  for (int ch = 0; ch < NCH; ++ch){
    int d = (blockIdx.x + ch*NBLK)*256 + t;
    float u[8], base[8], v[8]; int ix[8];
    #pragma unroll
    for (int i = 0; i < 8; ++i){
      size_t off = (size_t)i*DT + d;
      u[i] = U[off];
      base[i] = (LEVEL==2) ? s1*floorf(u[i]/s1) : vsum[off];
      v[i] = u[i] - base[i];
      ix[i] = i;
    }
    sort8kv(v, ix);                        // stable: reproduces jnp.argsort
    int cr = fr_s[code[d]];
    unsigned sb = bits_s[cr];
    // segmented mean scan (exact op order of the reference)
    float vv[8]; bool bl[8];
    float buf = 0.0f, cnt = 0.0f, g = 1.0f; bool reset = false;
    #pragma unroll
    for (int i = 0; i < 8; ++i){
      buf = reset ? v[i] : (buf + v[i]);
      cnt = reset ? 1.0f : (cnt + 1.0f);
      g   = reset ? 1.0f : g;
      float m = buf / cnt;
      if (i == 7){ vv[7] = g * m; bl[7] = true; }
      else {
        float msp = msp_s[cr*7 + i];
        bool b = ((sb >> i) & 1u) != 0u;
        vv[i] = b ? ((g * msp) * m) : 0.0f;
        bl[i] = b;
        g = b ? g : (g * (1.0f - msp));
        reset = b;
      }
    }
    float out = vv[7];
    float inner[8];
    inner[7] = out;
    for (int i = 6; i >= 0; --i){ if (bl[i]) out = vv[i]; inner[i] = out; }
    // per-row gather (inverse permutation) -> fully coalesced stores
    float res3[8];
    #pragma unroll
    for (int rr = 0; rr < 8; ++rr){
      float innr = inner[0];
      #pragma unroll
      for (int i = 1; i < 8; ++i) if (ix[i] == rr) innr = inner[i];
      if (ix[0] != rr && ix[1] != rr && ix[2] != rr && ix[3] != rr &&
          ix[4] != rr && ix[5] != rr && ix[6] != rr && ix[7] != rr) innr = inner[0]; // unreachable
      if (ix[0] == rr) innr = inner[0];
      float vnew = base[rr] + s * floorf(innr / s);
      vsum[(size_t)rr*DT + d] = vnew;
      if (LEVEL == 2) res3[rr] = u[rr] - vnew;   // bit-exact next-level residual
    }
    if (LEVEL == 2){                       // fused passA<3>
      sort8v(res3);
      float m = 0.0f;
      #pragma unroll
      for (int i = 0; i < 7; ++i) m = fmaxf(m, res3[i+1] - res3[i]);
      dmax = max(dmax, __float_as_uint(m));
    }
  }
  if (LEVEL == 2){
    sred[t] = dmax;
    __syncthreads();
    for (int o = 128; o > 0; o >>= 1){
      if (t < o) sred[t] = max(sred[t], sred[t+o]);
      __syncthreads();
    }
    if (t == 0) atomicMax(&meta[3], sred[0]);
  }
}

// transpose + convert: wt[n][l][k] = bf16(vsum[n][k][l])
__global__ __launch_bounds__(256) void k_wt(const float* __restrict__ vsum, unsigned short* __restrict__ wt){
  __shared__ unsigned short tile[64][68];
  int t = threadIdx.x;
  int c = t & 63, r0 = t >> 6;
  int n = blockIdx.z, k0 = blockIdx.y*64, l0 = blockIdx.x*64;
  const float* src = vsum + (size_t)n*DT;
  #pragma unroll
  for (int i = 0; i < 16; ++i){
    int r = r0 + i*4;
    tile[r][c] = f2bf(src[(size_t)(k0+r)*DD2 + l0 + c]);
  }
  __syncthreads();
  unsigned short* dst = wt + (size_t)n*DT;
  #pragma unroll
  for (int i = 0; i < 16; ++i){
    int r = r0 + i*4;   // l index within tile
    dst[(size_t)(l0+r)*DD1 + k0 + c] = tile[c][r];
  }
}

// MFMA GEMM: out[b,n,l] = sum_k x[b,n,k] * wt[n,l,k]; 128x128 tile, BK=64, 4 waves
__global__ __launch_bounds__(256) void k_gemm(const float* __restrict__ x,
                                              const unsigned short* __restrict__ wt,
                                              float* __restrict__ out){
  __shared__ __align__(16) unsigned short As[128][72];  // [b][k], pad 8 -> 16B-aligned frags
  __shared__ __align__(16) unsigned short Bs[128][72];  // [l][k]
  int t = threadIdx.x;
  int lane = t & 63, wv = t >> 6;
  int n  = blockIdx.z;
  int b0 = blockIdx.y * 128;
  int l0 = blockIdx.x * 128;
  int wm = (wv >> 1) * 64, wn = (wv & 1) * 64;
  f32x4 acc[4][4] = {};
  const unsigned short* wtn = wt + (size_t)n*DT;
  int col = lane & 15, quad = lane >> 4;
  for (int k0 = 0; k0 < DD1; k0 += 64){
    #pragma unroll
    for (int i = 0; i < 8; ++i){           // A: 128 rows x 16 float4 segs
      int cc = t + i*256;
      int row = cc >> 4, seg = cc & 15;
      float4 a = *(const float4*)(x + (((size_t)(b0+row)*NROW + n)*DD1 + k0 + seg*4));
      ushort4 h;
      h.x = f2bf(a.x); h.y = f2bf(a.y); h.z = f2bf(a.z); h.w = f2bf(a.w);
      *(ushort4*)&As[row][seg*4] = h;
    }
    #pragma unroll
    for (int i = 0; i < 4; ++i){           // B: 128 rows x 8 16B segs
      int cc = t + i*256;
      int row = cc >> 3, seg = cc & 7;
      uint4 b = *(const uint4*)(wtn + (size_t)(l0+row)*DD1 + k0 + seg*8);
      *(uint4*)&Bs[row][seg*8] = b;
    }
    __syncthreads();
    #pragma unroll
    for (int ks = 0; ks < 2; ++ks){
      int kq = ks*32 + quad*8;
      short8 af[4], bfr[4];
      #pragma unroll
      for (int mi = 0; mi < 4; ++mi) af[mi]  = *(const short8*)&As[wm + mi*16 + col][kq];
      #pragma unroll
      for (int ni = 0; ni < 4; ++ni) bfr[ni] = *(const short8*)&Bs[wn + ni*16 + col][kq];
      #pragma unroll
      for (int mi = 0; mi < 4; ++mi)
        #pragma unroll
        for (int ni = 0; ni < 4; ++ni)
          acc[mi][ni] = __builtin_amdgcn_mfma_f32_16x16x32_bf16(af[mi], bfr[ni], acc[mi][ni], 0, 0, 0);
    }
    __syncthreads();
  }
  #pragma unroll
  for (int mi = 0; mi < 4; ++mi)
    #pragma unroll
    for (int ni = 0; ni < 4; ++ni)
      #pragma unroll
      for (int r = 0; r < 4; ++r){
        int b = b0 + wm + mi*16 + quad*4 + r;
        int l = l0 + wn + ni*16 + col;
        out[((size_t)b*NROW + n)*DD2 + l] = acc[mi][ni][r];
      }
}

extern "C" void kernel_launch(void* const* d_in, const int* in_sizes, int n_in,
                              void* d_out, int out_size, void* d_ws, size_t ws_size,
                              hipStream_t stream){
  const float* x  = (const float*)d_in[0];
  const float* U  = (const float*)d_in[1];
  const float* tm = (const float*)d_in[2];
  float* out  = (float*)d_out;
  float* vsum = (float*)d_ws;
  unsigned char* code = (unsigned char*)d_ws + (size_t)NROW*DT*4;
  unsigned short* wt  = (unsigned short*)((unsigned char*)d_ws + (size_t)NROW*DT*4 + DT);
  unsigned* meta = (unsigned*)((unsigned char*)d_ws + (size_t)NROW*DT*4 + DT + (size_t)NROW*DT*2);
  (void)in_sizes; (void)n_in; (void)out_size; (void)ws_size;

  k_init  <<<1,    256, 0, stream>>>(meta);
  k_minmax<<<2048, 256, 0, stream>>>(U, meta);

  // level 2 (deno = 5)
  k_passA2  <<<NBLK, 256, 0, stream>>>(U, meta);
  k_passB<2><<<NBLK, 256, 0, stream>>>(U, vsum, tm, code, meta);
  k_small<2><<<1,   128, 0, stream>>>(U, vsum, tm, meta);
  k_passD<2><<<NBLK, 256, 0, stream>>>(U, vsum, code, meta);   // fuses passA<3>

  // level 3 (deno = 17)
  k_passB<3><<<NBLK, 256, 0, stream>>>(U, vsum, tm, code, meta);
  k_small<3><<<1,   128, 0, stream>>>(U, vsum, tm, meta);
  k_passD<3><<<NBLK, 256, 0, stream>>>(U, vsum, code, meta);

  // epilogue: transpose+convert weights, then bf16 MFMA GEMM
  k_wt  <<<dim3(DD2/64, DD1/64, NROW), 256, 0, stream>>>(vsum, wt);
  k_gemm<<<dim3(DD2/128, BATCH/128, NROW), 256, 0, stream>>>(x, wt, out);
}

// Round 3
// 475.897 us; speedup vs baseline: 2.1352x; 1.0023x over previous
//
#include <hip/hip_runtime.h>
#include <hip/hip_bf16.h>
#include <math.h>

#define NROW 8
#define DT   2097152   // D = D1*D2
#define DD1  2048
#define DD2  1024
#define BATCH 512
#define NBLK4 2048     // passes handling 4 cols/thread
#define NBLK2 4096     // passes handling 2 cols/thread

// ws layout:
//  [0)           vsum : NROW*DT floats            (67,108,864 B)   (xb bf16 reuses this after k_wt)
//  [67108864)    code : DT bytes                  ( 2,097,152 B)
//  [69206016)    wt   : NROW*DT bf16 [n][l][k]    (33,554,432 B)
//  [102760448)   meta : u32[1412]

typedef __attribute__((ext_vector_type(8))) short short8;
typedef __attribute__((ext_vector_type(4))) float f32x4;

__device__ __forceinline__ unsigned fenc(float f){
  unsigned u = __float_as_uint(f);
  return (u & 0x80000000u) ? ~u : (u | 0x80000000u);
}
__device__ __forceinline__ float fdec(unsigned k){
  return (k & 0x80000000u) ? __uint_as_float(k ^ 0x80000000u) : __uint_as_float(~k);
}
__device__ __forceinline__ float sigmoid_ref(float z){
  #pragma clang fp contract(off)
  return 1.0f / (1.0f + expf(-z));
}
__device__ __forceinline__ unsigned short f2bf(float f){
  __hip_bfloat16 h = __float2bfloat16(f);
  return *reinterpret_cast<unsigned short*>(&h);
}
// async global->LDS, 16B per lane; lds dest = wave-uniform base + lane*16
__device__ __forceinline__ void async16(const unsigned short* g, unsigned short* l){
  __builtin_amdgcn_global_load_lds((const __attribute__((address_space(1))) unsigned int*)g,
                                   (__attribute__((address_space(3))) unsigned int*)l, 16, 0, 0);
}

// ---- 8-element sorting networks (Batcher odd-even, 19 comparators) ----
#define CSWAPV(a,b) { float _lo=fminf(a,b), _hi=fmaxf(a,b); a=_lo; b=_hi; }
__device__ __forceinline__ void sort8v(float v[8]){
  CSWAPV(v[0],v[1]) CSWAPV(v[2],v[3]) CSWAPV(v[4],v[5]) CSWAPV(v[6],v[7])
  CSWAPV(v[0],v[2]) CSWAPV(v[1],v[3]) CSWAPV(v[4],v[6]) CSWAPV(v[5],v[7])
  CSWAPV(v[1],v[2]) CSWAPV(v[5],v[6])
  CSWAPV(v[0],v[4]) CSWAPV(v[1],v[5]) CSWAPV(v[2],v[6]) CSWAPV(v[3],v[7])
  CSWAPV(v[2],v[4]) CSWAPV(v[3],v[5])
  CSWAPV(v[1],v[2]) CSWAPV(v[3],v[4]) CSWAPV(v[5],v[6])
}
__device__ __forceinline__ void cswapkv(float&av,int&ai,float&bv,int&bi){
  bool sw = (av > bv) || ((av == bv) && (ai > bi));   // lexicographic -> stable
  float nav = sw ? bv : av; float nbv = sw ? av : bv;
  int   nai = sw ? bi : ai; int   nbi = sw ? ai : bi;
  av = nav; bv = nbv; ai = nai; bi = nbi;
}
#define CSWAPK(i,j) cswapkv(v[i],ix[i],v[j],ix[j]);
__device__ __forceinline__ void sort8kv(float v[8], int ix[8]){
  CSWAPK(0,1) CSWAPK(2,3) CSWAPK(4,5) CSWAPK(6,7)
  CSWAPK(0,2) CSWAPK(1,3) CSWAPK(4,6) CSWAPK(5,7)
  CSWAPK(1,2) CSWAPK(5,6)
  CSWAPK(0,4) CSWAPK(1,5) CSWAPK(2,6) CSWAPK(3,7)
  CSWAPK(2,4) CSWAPK(3,5)
  CSWAPK(1,2) CSWAPK(3,4) CSWAPK(5,6)
}

__global__ void k_init(unsigned* __restrict__ meta){
  int t = threadIdx.x;
  if (t == 0){ meta[0] = 0u; meta[1] = 0xFFFFFFFFu; meta[2] = 0u; meta[3] = 0u; }
  if (t < 128){ meta[4+t] = 0u; meta[132+t] = 0u; }
}

__global__ __launch_bounds__(256) void k_minmax(const float* __restrict__ U, unsigned* __restrict__ meta){
  __shared__ unsigned smx[256], smn[256];
  int t = threadIdx.x;
  size_t i = (size_t)blockIdx.x*256 + t;
  size_t stride = (size_t)gridDim.x*256;
  const float4* U4 = (const float4*)U;
  float mx = -INFINITY, mn = INFINITY;
  for (; i < (size_t)NROW*DT/4; i += stride){
    float4 v = U4[i];
    mx = fmaxf(fmaxf(mx,v.x), fmaxf(v.y, fmaxf(v.z,v.w)));
    mn = fminf(fminf(mn,v.x), fminf(v.y, fminf(v.z,v.w)));
  }
  smx[t] = fenc(mx); smn[t] = fenc(mn);
  __syncthreads();
  for (int o = 128; o > 0; o >>= 1){
    if (t < o){ smx[t] = max(smx[t], smx[t+o]); smn[t] = min(smn[t], smn[t+o]); }
    __syncthreads();
  }
  if (t == 0){ atomicMax(&meta[0], smx[0]); atomicMin(&meta[1], smn[0]); }
}

// level-2: max sorted-residual delta; 4 cols/thread, float4 loads
__global__ __launch_bounds__(256) void k_passA2(const float* __restrict__ U, unsigned* __restrict__ meta){
  #pragma clang fp contract(off)
  __shared__ unsigned sred[256];
  int t = threadIdx.x;
  int d0 = (blockIdx.x*256 + t)*4;
  float beta = fdec(meta[0]), alpha = fdec(meta[1]);
  float s1 = (beta - alpha) / 3.0f;
  float4 u[8];
  #pragma unroll
  for (int i = 0; i < 8; ++i) u[i] = *(const float4*)(U + (size_t)i*DT + d0);
  unsigned dmax = 0u;
  #pragma unroll
  for (int c = 0; c < 4; ++c){
    float res[8];
    #pragma unroll
    for (int i = 0; i < 8; ++i){
      float uv = ((const float*)&u[i])[c];
      res[i] = uv - s1*floorf(uv/s1);
    }
    sort8v(res);
    float m = 0.0f;
    #pragma unroll
    for (int i = 0; i < 7; ++i) m = fmaxf(m, res[i+1] - res[i]);
    dmax = max(dmax, __float_as_uint(m));   // deltas >= 0: bits order-preserving
  }
  sred[t] = dmax;
  __syncthreads();
  for (int o = 128; o > 0; o >>= 1){
    if (t < o) sred[t] = max(sred[t], sred[t+o]);
    __syncthreads();
  }
  if (t == 0) atomicMax(&meta[2], sred[0]);
}

template<int LEVEL>
__global__ __launch_bounds__(256) void k_passB(const float* __restrict__ U, const float* __restrict__ vsum,
                                               const float* __restrict__ thres_mean,
                                               unsigned char* __restrict__ code, unsigned* __restrict__ meta){
  #pragma clang fp contract(off)
  __shared__ int hist[128];
  int t = threadIdx.x;
  if (t < 128) hist[t] = 0;
  __syncthreads();
  int d0 = (blockIdx.x*256 + t)*4;
  float beta = fdec(meta[0]), alpha = fdec(meta[1]);
  float s1 = (beta - alpha) / 3.0f;
  float gmax = __uint_as_float(meta[(LEVEL==2)?2:3]);
  float4 u[8], b[8];
  #pragma unroll
  for (int i = 0; i < 8; ++i){
    u[i] = *(const float4*)(U + (size_t)i*DT + d0);
    if (LEVEL == 2){
      float4 bb;
      bb.x = s1*floorf(u[i].x/s1); bb.y = s1*floorf(u[i].y/s1);
      bb.z = s1*floorf(u[i].z/s1); bb.w = s1*floorf(u[i].w/s1);
      b[i] = bb;
    } else {
      b[i] = *(const float4*)(vsum + (size_t)i*DT + d0);
    }
  }
  float thr = sigmoid_ref(thres_mean[d0 >> 11]);   // 4-col group never crosses a D1 boundary
  uchar4 cods;
  unsigned char* cp = (unsigned char*)&cods;
  #pragma unroll
  for (int c = 0; c < 4; ++c){
    float res[8];
    #pragma unroll
    for (int i = 0; i < 8; ++i) res[i] = ((const float*)&u[i])[c] - ((const float*)&b[i])[c];
    sort8v(res);
    int cd = 0;
    #pragma unroll
    for (int i = 0; i < 7; ++i){
      float dn  = (res[i+1] - res[i]) / gmax;
      float z   = (dn - thr) / 0.01f;
      float msp = sigmoid_ref(z);
      int bit = (int)rintf(msp);                   // half-to-even like jnp.round
      cd = (cd << 1) | bit;                        // MSB-first
    }
    cp[c] = (unsigned char)cd;
    atomicAdd(&hist[cd], 1);
  }
  *(uchar4*)(code + d0) = cods;
  __syncthreads();
  if (t < 128 && hist[t] > 0) atomicAdd((int*)&meta[((LEVEL==2)?4:132) + t], hist[t]);
}

template<int LEVEL>
__global__ void k_small(const float* __restrict__ U, const float* __restrict__ vsum,
                        const float* __restrict__ thres_mean, unsigned* __restrict__ meta){
  #pragma clang fp contract(off)
  __shared__ int cs[128], rk[128], redk[128];
  __shared__ int top_code[5], top_rank[5];
  __shared__ int w0cnt;
  int c = threadIdx.x;                    // 128 threads
  cs[c] = (int)meta[((LEVEL==2)?4:132) + c];
  bool present = cs[c] > 0;
  unsigned long long bm = __ballot(present);
  int lane = c & 63;
  int r = (int)__popcll(bm & ((1ull << lane) - 1ull));
  if (c == 63) w0cnt = (int)__popcll(bm);
  __syncthreads();
  if (c >= 64) r += w0cnt;
  rk[c] = r;
  __syncthreads();
  for (int k = 0; k < 5; ++k){            // top-5 argsort(-counts), ties -> lowest index
    redk[c] = (cs[c] << 7) | (127 - c);
    __syncthreads();
    for (int o = 64; o > 0; o >>= 1){
      if (c < o) redk[c] = max(redk[c], redk[c+o]);
      __syncthreads();
    }
    if (c == 0){
      int best = 127 - (redk[0] & 127);
      top_code[k] = best; top_rank[k] = rk[best];
      cs[best] = -1;
    }
    __syncthreads();
  }
  int besti = -1, sel = 0;
  #pragma unroll
  for (int j = 0; j < 5; ++j){            // argmax first-wins over shared-bit counts
    int inter = __popc(c & top_code[j]);
    if (inter > besti){ besti = inter; sel = j; }
  }
  bool is_top = false;
  #pragma unroll
  for (int j = 0; j < 5; ++j) is_top = is_top || (rk[c] == top_rank[j]);
  int fr = is_top ? rk[c] : top_rank[sel];
  ((int*)meta)[260 + c] = fr;
  // msp/scheme table for columns 0..127 (the only ones c_rank can address)
  float beta = fdec(meta[0]), alpha = fdec(meta[1]);
  float s1 = (beta - alpha) / 3.0f;
  float gmax = __uint_as_float(meta[(LEVEL==2)?2:3]);
  float res[8];
  #pragma unroll
  for (int i = 0; i < 8; ++i){
    size_t off = (size_t)i*DT + c;
    float u = U[off];
    float b = (LEVEL==2) ? s1*floorf(u/s1) : vsum[off];
    res[i] = u - b;
  }
  sort8v(res);
  float thr = sigmoid_ref(thres_mean[c >> 11]);
  unsigned bits = 0;
  float* msp_tab = (float*)&meta[388];
  #pragma unroll
  for (int i = 0; i < 7; ++i){
    float dn  = (res[i+1] - res[i]) / gmax;
    float z   = (dn - thr) / 0.01f;
    float msp = sigmoid_ref(z);
    msp_tab[c*7 + i] = msp;
    bits |= ((unsigned)(int)rintf(msp)) << i;
  }
  meta[1284 + c] = bits;
}

// passD: apply segmented-mean quantization; LEVEL==2 fuses next level's passA. 2 cols/thread.
template<int LEVEL>
__global__ __launch_bounds__(256) void k_passD(const float* __restrict__ U, float* __restrict__ vsum,
                                               const unsigned char* __restrict__ code,
                                               unsigned* __restrict__ meta){
  #pragma clang fp contract(off)
  __shared__ int fr_s[128];
  __shared__ unsigned bits_s[128];
  __shared__ float msp_s[128*7];
  __shared__ unsigned sred[256];
  int t = threadIdx.x;
  if (t < 128){ fr_s[t] = ((int*)meta)[260 + t]; bits_s[t] = meta[1284 + t]; }
  for (int i = t; i < 128*7; i += 256) msp_s[i] = ((float*)&meta[388])[i];
  __syncthreads();
  int d0 = (blockIdx.x*256 + t)*2;
  float beta = fdec(meta[0]), alpha = fdec(meta[1]);
  float s1 = (beta - alpha) / 3.0f;
  float s2 = s1 / 5.0f;
  float s  = (LEVEL == 2) ? s2 : (s2 / 17.0f);
  float2 u2[8], b2[8];
  #pragma unroll
  for (int i = 0; i < 8; ++i){
    u2[i] = *(const float2*)(U + (size_t)i*DT + d0);
    if (LEVEL == 2){
      b2[i].x = s1*floorf(u2[i].x/s1);
      b2[i].y = s1*floorf(u2[i].y/s1);
    } else {
      b2[i] = *(const float2*)(vsum + (size_t)i*DT + d0);
    }
  }
  unsigned char cd2[2];
  *(ushort*)cd2 = *(const ushort*)(code + d0);
  float vnew[2][8];
  unsigned dmax = 0u;
  #pragma unroll
  for (int c = 0; c < 2; ++c){
    float v[8]; int ix[8];
    #pragma unroll
    for (int i = 0; i < 8; ++i){
      v[i] = ((const float*)&u2[i])[c] - ((const float*)&b2[i])[c];
      ix[i] = i;
    }
    sort8kv(v, ix);                        // stable: reproduces jnp.argsort
    int cr = fr_s[cd2[c]];
    unsigned sb = bits_s[cr];
    float vv[8]; bool bl[8];
    float buf = 0.0f, cnt = 0.0f, g = 1.0f; bool reset = false;
    #pragma unroll
    for (int i = 0; i < 8; ++i){           // exact op order of the reference scan
      buf = reset ? v[i] : (buf + v[i]);
      cnt = reset ? 1.0f : (cnt + 1.0f);
      g   = reset ? 1.0f : g;
      float m = buf / cnt;
      if (i == 7){ vv[7] = g * m; bl[7] = true; }
      else {
        float msp = msp_s[cr*7 + i];
        bool b = ((sb >> i) & 1u) != 0u;
        vv[i] = b ? ((g * msp) * m) : 0.0f;
        bl[i] = b;
        g = b ? g : (g * (1.0f - msp));
        reset = b;
      }
    }
    float out = vv[7];
    float inner[8];
    inner[7] = out;
    for (int i = 6; i >= 0; --i){ if (bl[i]) out = vv[i]; inner[i] = out; }
    float res3[8];
    #pragma unroll
    for (int rr = 0; rr < 8; ++rr){        // inverse permutation gather
      float innr = inner[0];
      #pragma unroll
      for (int i = 0; i < 8; ++i) innr = (ix[i] == rr) ? inner[i] : innr;
      float vn = ((const float*)&b2[rr])[c] + s * floorf(innr / s);
      vnew[c][rr] = vn;
      if (LEVEL == 2) res3[rr] = ((const float*)&u2[rr])[c] - vn;  // bit-exact next residual
    }
    if (LEVEL == 2){                       // fused passA<3>
      sort8v(res3);
      float m = 0.0f;
      #pragma unroll
      for (int i = 0; i < 7; ++i) m = fmaxf(m, res3[i+1] - res3[i]);
      dmax = max(dmax, __float_as_uint(m));
    }
  }
  #pragma unroll
  for (int rr = 0; rr < 8; ++rr){
    float2 o; o.x = vnew[0][rr]; o.y = vnew[1][rr];
    *(float2*)(vsum + (size_t)rr*DT + d0) = o;
  }
  if (LEVEL == 2){
    sred[t] = dmax;
    __syncthreads();
    for (int o = 128; o > 0; o >>= 1){
      if (t < o) sred[t] = max(sred[t], sred[t+o]);
      __syncthreads();
    }
    if (t == 0) atomicMax(&meta[3], sred[0]);
  }
}

// transpose + convert: wt[n][l][k] = bf16(vsum[n][k][l]); 64(k) x 64(l) tiles
__global__ __launch_bounds__(256) void k_wt(const float* __restrict__ vsum, unsigned short* __restrict__ wt){
  __shared__ unsigned short tile[64][68];
  int t = threadIdx.x;
  int c4 = t & 15, r0 = t >> 4;            // 16 rows per sweep
  int n = blockIdx.z, k0 = blockIdx.y*64, l0 = blockIdx.x*64;
  const float* src = vsum + (size_t)n*DT;
  #pragma unroll
  for (int i = 0; i < 4; ++i){
    int r = r0 + i*16;                     // k index in tile
    float4 v = *(const float4*)(src + (size_t)(k0+r)*DD2 + l0 + c4*4);
    tile[r][c4*4+0] = f2bf(v.x); tile[r][c4*4+1] = f2bf(v.y);
    tile[r][c4*4+2] = f2bf(v.z); tile[r][c4*4+3] = f2bf(v.w);
  }
  __syncthreads();
  unsigned short* dst = wt + (size_t)n*DT;
  #pragma unroll
  for (int i = 0; i < 4; ++i){
    int rl = r0 + i*16;                    // l index in tile
    ushort4 o;
    o.x = tile[c4*4+0][rl]; o.y = tile[c4*4+1][rl];
    o.z = tile[c4*4+2][rl]; o.w = tile[c4*4+3][rl];
    *(ushort4*)(dst + (size_t)(l0+rl)*DD1 + k0 + c4*4) = o;
  }
}

// x fp32 -> bf16, same layout
__global__ __launch_bounds__(256) void k_xb(const float* __restrict__ x, unsigned short* __restrict__ xb){
  int idx = (blockIdx.x*256 + threadIdx.x)*4;
  float4 v = *(const float4*)(x + idx);
  ushort4 o;
  o.x = f2bf(v.x); o.y = f2bf(v.y); o.z = f2bf(v.z); o.w = f2bf(v.w);
  *(ushort4*)(xb + idx) = o;
}

// MFMA GEMM: out[b,n,l] = sum_k xb[b,n,k] * wt[n,l,k]; 64(M)x128(N) tile, BK=64, 4 waves
__global__ __launch_bounds__(256) void k_gemm(const unsigned short* __restrict__ xb,
                                              const unsigned short* __restrict__ wt,
                                              float* __restrict__ out){
  __shared__ __align__(16) unsigned short As[64*64];    // [m][k] unpadded (async layout)
  __shared__ __align__(16) unsigned short Bs[128*64];   // [l][k] unpadded
  int t = threadIdx.x;
  int lane = t & 63, wv = t >> 6;
  int n  = blockIdx.z;
  int b0 = blockIdx.y * 64;
  int l0 = blockIdx.x * 128;
  int wm = (wv >> 1) * 32, wn = (wv & 1) * 64;
  int col = lane & 15, quad = lane >> 4;
  int arow = lane >> 3, aseg = lane & 7;
  const unsigned short* wtn = wt + (size_t)n*DT;
  f32x4 acc[2][4] = {};
  for (int k0 = 0; k0 < DD1; k0 += 64){
    #pragma unroll
    for (int i = 0; i < 2; ++i){            // A: 64 rows, wave w covers rows [w*16, w*16+16)
      int row = wv*16 + i*8 + arow;
      const unsigned short* g = xb + (((size_t)(b0+row)*NROW + n)*DD1 + k0 + aseg*8);
      async16(g, &As[(wv*16 + i*8)*64]);
    }
    #pragma unroll
    for (int i = 0; i < 4; ++i){            // B: 128 rows, wave w covers rows [w*32, w*32+32)
      int row = wv*32 + i*8 + arow;
      const unsigned short* g = wtn + ((size_t)(l0+row)*DD1 + k0 + aseg*8);
      async16(g, &Bs[(wv*32 + i*8)*64]);
    }
    __syncthreads();                        // drains vmcnt before barrier
    #pragma unroll
    for (int ks = 0; ks < 2; ++ks){
      int kq = ks*32 + quad*8;
      short8 af[2], bfr[4];
      #pragma unroll
      for (int mi = 0; mi < 2; ++mi) af[mi]  = *(const short8*)&As[(wm + mi*16 + col)*64 + kq];
      #pragma unroll
      for (int ni = 0; ni < 4; ++ni) bfr[ni] = *(const short8*)&Bs[(wn + ni*16 + col)*64 + kq];
      #pragma unroll
      for (int mi = 0; mi < 2; ++mi)
        #pragma unroll
        for (int ni = 0; ni < 4; ++ni)
          acc[mi][ni] = __builtin_amdgcn_mfma_f32_16x16x32_bf16(af[mi], bfr[ni], acc[mi][ni], 0, 0, 0);
    }
    __syncthreads();
  }
  #pragma unroll
  for (int mi = 0; mi < 2; ++mi)
    #pragma unroll
    for (int ni = 0; ni < 4; ++ni)
      #pragma unroll
      for (int r = 0; r < 4; ++r){
        int b = b0 + wm + mi*16 + quad*4 + r;
        int l = l0 + wn + ni*16 + col;
        out[((size_t)b*NROW + n)*DD2 + l] = acc[mi][ni][r];
      }
}

extern "C" void kernel_launch(void* const* d_in, const int* in_sizes, int n_in,
                              void* d_out, int out_size, void* d_ws, size_t ws_size,
                              hipStream_t stream){
  const float* x  = (const float*)d_in[0];
  const float* U  = (const float*)d_in[1];
  const float* tm = (const float*)d_in[2];
  float* out  = (float*)d_out;
  float* vsum = (float*)d_ws;
  unsigned char* code = (unsigned char*)d_ws + (size_t)NROW*DT*4;
  unsigned short* wt  = (unsigned short*)((unsigned char*)d_ws + (size_t)NROW*DT*4 + DT);
  unsigned* meta = (unsigned*)((unsigned char*)d_ws + (size_t)NROW*DT*4 + DT + (size_t)NROW*DT*2);
  unsigned short* xb = (unsigned short*)d_ws;   // overlaps vsum; written only after k_wt
  (void)in_sizes; (void)n_in; (void)out_size; (void)ws_size;

  k_init  <<<1,    256, 0, stream>>>(meta);
  k_minmax<<<2048, 256, 0, stream>>>(U, meta);

  // level 2 (deno = 5)
  k_passA2  <<<NBLK4, 256, 0, stream>>>(U, meta);
  k_passB<2><<<NBLK4, 256, 0, stream>>>(U, vsum, tm, code, meta);
  k_small<2><<<1,    128, 0, stream>>>(U, vsum, tm, meta);
  k_passD<2><<<NBLK2, 256, 0, stream>>>(U, vsum, code, meta);   // fuses passA<3>

  // level 3 (deno = 17)
  k_passB<3><<<NBLK4, 256, 0, stream>>>(U, vsum, tm, code, meta);
  k_small<3><<<1,    128, 0, stream>>>(U, vsum, tm, meta);
  k_passD<3><<<NBLK2, 256, 0, stream>>>(U, vsum, code, meta);

  // epilogue
  k_wt  <<<dim3(DD2/64, DD1/64, NROW), 256, 0, stream>>>(vsum, wt);
  k_xb  <<<(BATCH*NROW*DD1)/1024, 256, 0, stream>>>(x, xb);
  k_gemm<<<dim3(DD2/128, BATCH/64, NROW), 256, 0, stream>>>(xb, wt, out);
}

// Round 4
// 428.689 us; speedup vs baseline: 2.3703x; 1.1101x over previous
//
#include <hip/hip_runtime.h>
#include <hip/hip_bf16.h>
#include <math.h>

#define NROW 8
#define DT   2097152   // D = D1*D2
#define DD1  2048
#define DD2  1024
#define BATCH 512
#define NBLK4 2048     // passes handling 4 cols/thread (2048*256*4 == DT)

// ws layout (unchanged from R3, ~103 MB):
//  [0)           vsum : NROW*DT floats            (67,108,864 B)   (xb bf16 reuses this after k_wt)
//  [67108864)    code : DT bytes                  ( 2,097,152 B)
//  [69206016)    wt   : NROW*DT bf16 [n][l][k]    (33,554,432 B)
//  [102760448)   meta : u32[1412]

typedef __attribute__((ext_vector_type(8))) short short8;
typedef __attribute__((ext_vector_type(4))) float f32x4;

__device__ __forceinline__ unsigned fenc(float f){
  unsigned u = __float_as_uint(f);
  return (u & 0x80000000u) ? ~u : (u | 0x80000000u);
}
__device__ __forceinline__ float fdec(unsigned k){
  return (k & 0x80000000u) ? __uint_as_float(k ^ 0x80000000u) : __uint_as_float(~k);
}
__device__ __forceinline__ float sigmoid_ref(float z){
  #pragma clang fp contract(off)
  return 1.0f / (1.0f + expf(-z));
}
__device__ __forceinline__ unsigned short f2bf(float f){
  __hip_bfloat16 h = __float2bfloat16(f);
  return *reinterpret_cast<unsigned short*>(&h);
}
// consistent level-1 base across ALL kernels: s1*floor(u*inv_s1)
__device__ __forceinline__ float base1(float u, float s1, float inv_s1){
  #pragma clang fp contract(off)
  return s1 * floorf(u * inv_s1);
}
// async global->LDS, 16B per lane
__device__ __forceinline__ void async16(const unsigned short* g, unsigned short* l){
  __builtin_amdgcn_global_load_lds((const __attribute__((address_space(1))) unsigned int*)g,
                                   (__attribute__((address_space(3))) unsigned int*)l, 16, 0, 0);
}

// ---- 8-element sorting networks (Batcher odd-even, 19 comparators) ----
#define CSWAPV(a,b) { float _lo=fminf(a,b), _hi=fmaxf(a,b); a=_lo; b=_hi; }
__device__ __forceinline__ void sort8v(float v[8]){
  CSWAPV(v[0],v[1]) CSWAPV(v[2],v[3]) CSWAPV(v[4],v[5]) CSWAPV(v[6],v[7])
  CSWAPV(v[0],v[2]) CSWAPV(v[1],v[3]) CSWAPV(v[4],v[6]) CSWAPV(v[5],v[7])
  CSWAPV(v[1],v[2]) CSWAPV(v[5],v[6])
  CSWAPV(v[0],v[4]) CSWAPV(v[1],v[5]) CSWAPV(v[2],v[6]) CSWAPV(v[3],v[7])
  CSWAPV(v[2],v[4]) CSWAPV(v[3],v[5])
  CSWAPV(v[1],v[2]) CSWAPV(v[3],v[4]) CSWAPV(v[5],v[6])
}
__device__ __forceinline__ void cswapkv(float&av,int&ai,float&bv,int&bi){
  bool sw = (av > bv) || ((av == bv) && (ai > bi));   // lexicographic -> stable
  float nav = sw ? bv : av; float nbv = sw ? av : bv;
  int   nai = sw ? bi : ai; int   nbi = sw ? ai : bi;
  av = nav; bv = nbv; ai = nai; bi = nbi;
}
#define CSWAPK(i,j) cswapkv(v[i],ix[i],v[j],ix[j]);
__device__ __forceinline__ void sort8kv(float v[8], int ix[8]){
  CSWAPK(0,1) CSWAPK(2,3) CSWAPK(4,5) CSWAPK(6,7)
  CSWAPK(0,2) CSWAPK(1,3) CSWAPK(4,6) CSWAPK(5,7)
  CSWAPK(1,2) CSWAPK(5,6)
  CSWAPK(0,4) CSWAPK(1,5) CSWAPK(2,6) CSWAPK(3,7)
  CSWAPK(2,4) CSWAPK(3,5)
  CSWAPK(1,2) CSWAPK(3,4) CSWAPK(5,6)
}

__global__ void k_init(unsigned* __restrict__ meta){
  int t = threadIdx.x;
  if (t == 0){ meta[0] = 0u; meta[1] = 0xFFFFFFFFu; meta[2] = 0u; meta[3] = 0u; }
  if (t < 128){ meta[4+t] = 0u; meta[132+t] = 0u; }
}

__global__ __launch_bounds__(256) void k_minmax(const float* __restrict__ U, unsigned* __restrict__ meta){
  __shared__ unsigned smx[256], smn[256];
  int t = threadIdx.x;
  size_t i = (size_t)blockIdx.x*256 + t;
  size_t stride = (size_t)gridDim.x*256;
  const float4* U4 = (const float4*)U;
  float mx = -INFINITY, mn = INFINITY;
  for (; i < (size_t)NROW*DT/4; i += stride){
    float4 v = U4[i];
    mx = fmaxf(fmaxf(mx,v.x), fmaxf(v.y, fmaxf(v.z,v.w)));
    mn = fminf(fminf(mn,v.x), fminf(v.y, fminf(v.z,v.w)));
  }
  smx[t] = fenc(mx); smn[t] = fenc(mn);
  __syncthreads();
  for (int o = 128; o > 0; o >>= 1){
    if (t < o){ smx[t] = max(smx[t], smx[t+o]); smn[t] = min(smn[t], smn[t+o]); }
    __syncthreads();
  }
  if (t == 0){ atomicMax(&meta[0], smx[0]); atomicMin(&meta[1], smn[0]); }
}

// level-2: max sorted-residual delta; 4 cols/thread, float4 loads
__global__ __launch_bounds__(256) void k_passA2(const float* __restrict__ U, unsigned* __restrict__ meta){
  #pragma clang fp contract(off)
  __shared__ unsigned sred[256];
  int t = threadIdx.x;
  int d0 = (blockIdx.x*256 + t)*4;
  float beta = fdec(meta[0]), alpha = fdec(meta[1]);
  float s1 = (beta - alpha) / 3.0f;
  float inv_s1 = 1.0f / s1;
  float4 u[8];
  #pragma unroll
  for (int i = 0; i < 8; ++i) u[i] = *(const float4*)(U + (size_t)i*DT + d0);
  unsigned dmax = 0u;
  #pragma unroll
  for (int c = 0; c < 4; ++c){
    float res[8];
    #pragma unroll
    for (int i = 0; i < 8; ++i){
      float uv = ((const float*)&u[i])[c];
      res[i] = uv - base1(uv, s1, inv_s1);
    }
    sort8v(res);
    float m = 0.0f;
    #pragma unroll
    for (int i = 0; i < 7; ++i) m = fmaxf(m, res[i+1] - res[i]);
    dmax = max(dmax, __float_as_uint(m));   // deltas >= 0: bits order-preserving
  }
  sred[t] = dmax;
  __syncthreads();
  for (int o = 128; o > 0; o >>= 1){
    if (t < o) sred[t] = max(sred[t], sred[t+o]);
    __syncthreads();
  }
  if (t == 0) atomicMax(&meta[2], sred[0]);
}

template<int LEVEL>
__global__ __launch_bounds__(256) void k_passB(const float* __restrict__ U, const float* __restrict__ vsum,
                                               const float* __restrict__ thres_mean,
                                               unsigned char* __restrict__ code, unsigned* __restrict__ meta){
  #pragma clang fp contract(off)
  __shared__ int hist[128];
  int t = threadIdx.x;
  if (t < 128) hist[t] = 0;
  __syncthreads();
  int d0 = (blockIdx.x*256 + t)*4;
  float beta = fdec(meta[0]), alpha = fdec(meta[1]);
  float s1 = (beta - alpha) / 3.0f;
  float inv_s1 = 1.0f / s1;
  float gmax = __uint_as_float(meta[(LEVEL==2)?2:3]);
  float inv_gmax = 1.0f / gmax;
  float4 u[8], b[8];
  #pragma unroll
  for (int i = 0; i < 8; ++i){
    u[i] = *(const float4*)(U + (size_t)i*DT + d0);
    if (LEVEL == 2){
      float4 bb;
      bb.x = base1(u[i].x, s1, inv_s1); bb.y = base1(u[i].y, s1, inv_s1);
      bb.z = base1(u[i].z, s1, inv_s1); bb.w = base1(u[i].w, s1, inv_s1);
      b[i] = bb;
    } else {
      b[i] = *(const float4*)(vsum + (size_t)i*DT + d0);
    }
  }
  float thr = sigmoid_ref(thres_mean[d0 >> 11]);   // 4-col group never crosses a D1 boundary
  uchar4 cods;
  unsigned char* cp = (unsigned char*)&cods;
  #pragma unroll
  for (int c = 0; c < 4; ++c){
    float res[8];
    #pragma unroll
    for (int i = 0; i < 8; ++i) res[i] = ((const float*)&u[i])[c] - ((const float*)&b[i])[c];
    sort8v(res);
    int cd = 0;
    #pragma unroll
    for (int i = 0; i < 7; ++i){
      // bit = rint(sigmoid((dn-thr)/0.01)) == (dn > thr)  (sigmoid>0.5 <=> z>0; ties -> 0 both ways)
      float dn = (res[i+1] - res[i]) * inv_gmax;
      int bit = (dn > thr) ? 1 : 0;
      cd = (cd << 1) | bit;                        // MSB-first
    }
    cp[c] = (unsigned char)cd;
    atomicAdd(&hist[cd], 1);
  }
  *(uchar4*)(code + d0) = cods;
  __syncthreads();
  if (t < 128 && hist[t] > 0) atomicAdd((int*)&meta[((LEVEL==2)?4:132) + t], hist[t]);
}

template<int LEVEL>
__global__ void k_small(const float* __restrict__ U, const float* __restrict__ vsum,
                        const float* __restrict__ thres_mean, unsigned* __restrict__ meta){
  #pragma clang fp contract(off)
  __shared__ int cs[128], rk[128], redk[128];
  __shared__ int top_code[5], top_rank[5];
  __shared__ int w0cnt;
  int c = threadIdx.x;                    // 128 threads
  cs[c] = (int)meta[((LEVEL==2)?4:132) + c];
  bool present = cs[c] > 0;
  unsigned long long bm = __ballot(present);
  int lane = c & 63;
  int r = (int)__popcll(bm & ((1ull << lane) - 1ull));
  if (c == 63) w0cnt = (int)__popcll(bm);
  __syncthreads();
  if (c >= 64) r += w0cnt;
  rk[c] = r;
  __syncthreads();
  for (int k = 0; k < 5; ++k){            // top-5 argsort(-counts), ties -> lowest index
    redk[c] = (cs[c] << 7) | (127 - c);
    __syncthreads();
    for (int o = 64; o > 0; o >>= 1){
      if (c < o) redk[c] = max(redk[c], redk[c+o]);
      __syncthreads();
    }
    if (c == 0){
      int best = 127 - (redk[0] & 127);
      top_code[k] = best; top_rank[k] = rk[best];
      cs[best] = -1;
    }
    __syncthreads();
  }
  int besti = -1, sel = 0;
  #pragma unroll
  for (int j = 0; j < 5; ++j){            // argmax first-wins over shared-bit counts
    int inter = __popc(c & top_code[j]);
    if (inter > besti){ besti = inter; sel = j; }
  }
  bool is_top = false;
  #pragma unroll
  for (int j = 0; j < 5; ++j) is_top = is_top || (rk[c] == top_rank[j]);
  int fr = is_top ? rk[c] : top_rank[sel];
  ((int*)meta)[260 + c] = fr;
  // msp/scheme table for columns 0..127: full-fidelity sigmoid (values multiply into w)
  float beta = fdec(meta[0]), alpha = fdec(meta[1]);
  float s1 = (beta - alpha) / 3.0f;
  float inv_s1 = 1.0f / s1;
  float gmax = __uint_as_float(meta[(LEVEL==2)?2:3]);
  float res[8];
  #pragma unroll
  for (int i = 0; i < 8; ++i){
    size_t off = (size_t)i*DT + c;
    float u = U[off];
    float b = (LEVEL==2) ? base1(u, s1, inv_s1) : vsum[off];
    res[i] = u - b;
  }
  sort8v(res);
  float thr = sigmoid_ref(thres_mean[c >> 11]);
  unsigned bits = 0;
  float* msp_tab = (float*)&meta[388];
  #pragma unroll
  for (int i = 0; i < 7; ++i){
    float dn  = (res[i+1] - res[i]) / gmax;
    float z   = (dn - thr) / 0.01f;
    float msp = sigmoid_ref(z);
    msp_tab[c*7 + i] = msp;
    bits |= ((unsigned)(int)rintf(msp)) << i;
  }
  meta[1284 + c] = bits;
}

// passD: segmented-mean quantization, 4 cols/thread; LEVEL==2 fuses next level's passA.
// Inverse permutation via LDS scatter: bank = t%32 -> conflict-free even with divergent ix.
template<int LEVEL>
__global__ __launch_bounds__(256) void k_passD(const float* __restrict__ U, float* __restrict__ vsum,
                                               const unsigned char* __restrict__ code,
                                               unsigned* __restrict__ meta){
  #pragma clang fp contract(off)
  __shared__ float q_lds[32*256];          // [rr*4+c][t]
  __shared__ int fr_s[128];
  __shared__ unsigned bits_s[128];
  __shared__ float msp_s[128*7];
  __shared__ unsigned sred[256];
  int t = threadIdx.x;
  if (t < 128){ fr_s[t] = ((int*)meta)[260 + t]; bits_s[t] = meta[1284 + t]; }
  for (int i = t; i < 128*7; i += 256) msp_s[i] = ((float*)&meta[388])[i];
  __syncthreads();
  int d0 = (blockIdx.x*256 + t)*4;
  float beta = fdec(meta[0]), alpha = fdec(meta[1]);
  float s1 = (beta - alpha) / 3.0f;
  float inv_s1 = 1.0f / s1;
  float s2 = s1 / 5.0f;
  float s  = (LEVEL == 2) ? s2 : (s2 / 17.0f);
  float inv_s = 1.0f / s;
  float4 u4[8], b4[8];
  #pragma unroll
  for (int i = 0; i < 8; ++i){
    u4[i] = *(const float4*)(U + (size_t)i*DT + d0);
    if (LEVEL == 2){
      float4 bb;
      bb.x = base1(u4[i].x, s1, inv_s1); bb.y = base1(u4[i].y, s1, inv_s1);
      bb.z = base1(u4[i].z, s1, inv_s1); bb.w = base1(u4[i].w, s1, inv_s1);
      b4[i] = bb;
    } else {
      b4[i] = *(const float4*)(vsum + (size_t)i*DT + d0);
    }
  }
  uchar4 cods = *(const uchar4*)(code + d0);
  const unsigned char* cp = (const unsigned char*)&cods;
  #pragma unroll
  for (int c = 0; c < 4; ++c){
    float v[8]; int ix[8];
    #pragma unroll
    for (int i = 0; i < 8; ++i){
      v[i] = ((const float*)&u4[i])[c] - ((const float*)&b4[i])[c];
      ix[i] = i;
    }
    sort8kv(v, ix);                        // stable: reproduces jnp.argsort
    int cr = fr_s[cp[c]];
    unsigned sb = bits_s[cr];
    float vv[8]; bool bl[8];
    float buf = 0.0f, cnt = 0.0f, g = 1.0f; bool reset = false;
    #pragma unroll
    for (int i = 0; i < 8; ++i){           // reference scan; mean via rcp (<=1.5ulp)
      buf = reset ? v[i] : (buf + v[i]);
      cnt = reset ? 1.0f : (cnt + 1.0f);
      g   = reset ? 1.0f : g;
      float m = buf * __builtin_amdgcn_rcpf(cnt);
      if (i == 7){ vv[7] = g * m; bl[7] = true; }
      else {
        float msp = msp_s[cr*7 + i];
        bool b = ((sb >> i) & 1u) != 0u;
        vv[i] = b ? ((g * msp) * m) : 0.0f;
        bl[i] = b;
        g = b ? g : (g * (1.0f - msp));
        reset = b;
      }
    }
    float out = vv[7];
    float inner[8];
    inner[7] = out;
    for (int i = 6; i >= 0; --i){ if (bl[i]) out = vv[i]; inner[i] = out; }
    #pragma unroll
    for (int i = 0; i < 8; ++i){           // scatter q to original-row slot
      float q = s * floorf(inner[i] * inv_s);
      q_lds[(ix[i]*4 + c)*256 + t] = q;
    }
  }
  // gather per original row; coalesced float4 stores
  float4 vn4[8];
  unsigned dmax = 0u;
  #pragma unroll
  for (int c = 0; c < 4; ++c){
    float res3[8];
    #pragma unroll
    for (int rr = 0; rr < 8; ++rr){
      float q = q_lds[(rr*4 + c)*256 + t];
      float vn = ((const float*)&b4[rr])[c] + q;
      ((float*)&vn4[rr])[c] = vn;
      if (LEVEL == 2) res3[rr] = ((const float*)&u4[rr])[c] - vn;  // bit-exact next residual
    }
    if (LEVEL == 2){                       // fused passA<3>
      sort8v(res3);
      float m = 0.0f;
      #pragma unroll
      for (int i = 0; i < 7; ++i) m = fmaxf(m, res3[i+1] - res3[i]);
      dmax = max(dmax, __float_as_uint(m));
    }
  }
  #pragma unroll
  for (int rr = 0; rr < 8; ++rr)
    *(float4*)(vsum + (size_t)rr*DT + d0) = vn4[rr];
  if (LEVEL == 2){
    sred[t] = dmax;
    __syncthreads();
    for (int o = 128; o > 0; o >>= 1){
      if (t < o) sred[t] = max(sred[t], sred[t+o]);
      __syncthreads();
    }
    if (t == 0) atomicMax(&meta[3], sred[0]);
  }
}

// transpose + convert: wt[n][l][k] = bf16(vsum[n][k][l]); 64(k) x 64(l) tiles
__global__ __launch_bounds__(256) void k_wt(const float* __restrict__ vsum, unsigned short* __restrict__ wt){
  __shared__ unsigned short tile[64][68];
  int t = threadIdx.x;
  int c4 = t & 15, r0 = t >> 4;            // 16 rows per sweep
  int n = blockIdx.z, k0 = blockIdx.y*64, l0 = blockIdx.x*64;
  const float* src = vsum + (size_t)n*DT;
  #pragma unroll
  for (int i = 0; i < 4; ++i){
    int r = r0 + i*16;                     // k index in tile
    float4 v = *(const float4*)(src + (size_t)(k0+r)*DD2 + l0 + c4*4);
    tile[r][c4*4+0] = f2bf(v.x); tile[r][c4*4+1] = f2bf(v.y);
    tile[r][c4*4+2] = f2bf(v.z); tile[r][c4*4+3] = f2bf(v.w);
  }
  __syncthreads();
  unsigned short* dst = wt + (size_t)n*DT;
  #pragma unroll
  for (int i = 0; i < 4; ++i){
    int rl = r0 + i*16;                    // l index in tile
    ushort4 o;
    o.x = tile[c4*4+0][rl]; o.y = tile[c4*4+1][rl];
    o.z = tile[c4*4+2][rl]; o.w = tile[c4*4+3][rl];
    *(ushort4*)(dst + (size_t)(l0+rl)*DD1 + k0 + c4*4) = o;
  }
}

// x fp32 -> bf16, same layout
__global__ __launch_bounds__(256) void k_xb(const float* __restrict__ x, unsigned short* __restrict__ xb){
  int idx = (blockIdx.x*256 + threadIdx.x)*4;
  float4 v = *(const float4*)(x + idx);
  ushort4 o;
  o.x = f2bf(v.x); o.y = f2bf(v.y); o.z = f2bf(v.z); o.w = f2bf(v.w);
  *(ushort4*)(xb + idx) = o;
}

// MFMA GEMM: out[b,n,l] = sum_k xb[b,n,k] * wt[n,l,k]; 64(M)x128(N) tile, BK=64, 4 waves
__global__ __launch_bounds__(256) void k_gemm(const unsigned short* __restrict__ xb,
                                              const unsigned short* __restrict__ wt,
                                              float* __restrict__ out){
  __shared__ __align__(16) unsigned short As[64*64];    // [m][k] unpadded (async layout)
  __shared__ __align__(16) unsigned short Bs[128*64];   // [l][k] unpadded
  int t = threadIdx.x;
  int lane = t & 63, wv = t >> 6;
  int n  = blockIdx.z;
  int b0 = blockIdx.y * 64;
  int l0 = blockIdx.x * 128;
  int wm = (wv >> 1) * 32, wn = (wv & 1) * 64;
  int col = lane & 15, quad = lane >> 4;
  int arow = lane >> 3, aseg = lane & 7;
  const unsigned short* wtn = wt + (size_t)n*DT;
  f32x4 acc[2][4] = {};
  for (int k0 = 0; k0 < DD1; k0 += 64){
    #pragma unroll
    for (int i = 0; i < 2; ++i){            // A: 64 rows, wave w covers rows [w*16, w*16+16)
      int row = wv*16 + i*8 + arow;
      const unsigned short* g = xb + (((size_t)(b0+row)*NROW + n)*DD1 + k0 + aseg*8);
      async16(g, &As[(wv*16 + i*8)*64]);
    }
    #pragma unroll
    for (int i = 0; i < 4; ++i){            // B: 128 rows, wave w covers rows [w*32, w*32+32)
      int row = wv*32 + i*8 + arow;
      const unsigned short* g = wtn + ((size_t)(l0+row)*DD1 + k0 + aseg*8);
      async16(g, &Bs[(wv*32 + i*8)*64]);
    }
    __syncthreads();
    #pragma unroll
    for (int ks = 0; ks < 2; ++ks){
      int kq = ks*32 + quad*8;
      short8 af[2], bfr[4];
      #pragma unroll
      for (int mi = 0; mi < 2; ++mi) af[mi]  = *(const short8*)&As[(wm + mi*16 + col)*64 + kq];
      #pragma unroll
      for (int ni = 0; ni < 4; ++ni) bfr[ni] = *(const short8*)&Bs[(wn + ni*16 + col)*64 + kq];
      #pragma unroll
      for (int mi = 0; mi < 2; ++mi)
        #pragma unroll
        for (int ni = 0; ni < 4; ++ni)
          acc[mi][ni] = __builtin_amdgcn_mfma_f32_16x16x32_bf16(af[mi], bfr[ni], acc[mi][ni], 0, 0, 0);
    }
    __syncthreads();
  }
  #pragma unroll
  for (int mi = 0; mi < 2; ++mi)
    #pragma unroll
    for (int ni = 0; ni < 4; ++ni)
      #pragma unroll
      for (int r = 0; r < 4; ++r){
        int b = b0 + wm + mi*16 + quad*4 + r;
        int l = l0 + wn + ni*16 + col;
        out[((size_t)b*NROW + n)*DD2 + l] = acc[mi][ni][r];
      }
}

extern "C" void kernel_launch(void* const* d_in, const int* in_sizes, int n_in,
                              void* d_out, int out_size, void* d_ws, size_t ws_size,
                              hipStream_t stream){
  const float* x  = (const float*)d_in[0];
  const float* U  = (const float*)d_in[1];
  const float* tm = (const float*)d_in[2];
  float* out  = (float*)d_out;
  float* vsum = (float*)d_ws;
  unsigned char* code = (unsigned char*)d_ws + (size_t)NROW*DT*4;
  unsigned short* wt  = (unsigned short*)((unsigned char*)d_ws + (size_t)NROW*DT*4 + DT);
  unsigned* meta = (unsigned*)((unsigned char*)d_ws + (size_t)NROW*DT*4 + DT + (size_t)NROW*DT*2);
  unsigned short* xb = (unsigned short*)d_ws;   // overlaps vsum; written only after k_wt
  (void)in_sizes; (void)n_in; (void)out_size; (void)ws_size;

  k_init  <<<1,    256, 0, stream>>>(meta);
  k_minmax<<<2048, 256, 0, stream>>>(U, meta);

  // level 2 (deno = 5)
  k_passA2  <<<NBLK4, 256, 0, stream>>>(U, meta);
  k_passB<2><<<NBLK4, 256, 0, stream>>>(U, vsum, tm, code, meta);
  k_small<2><<<1,    128, 0, stream>>>(U, vsum, tm, meta);
  k_passD<2><<<NBLK4, 256, 0, stream>>>(U, vsum, code, meta);   // fuses passA<3>

  // level 3 (deno = 17)
  k_passB<3><<<NBLK4, 256, 0, stream>>>(U, vsum, tm, code, meta);
  k_small<3><<<1,    128, 0, stream>>>(U, vsum, tm, meta);
  k_passD<3><<<NBLK4, 256, 0, stream>>>(U, vsum, code, meta);

  // epilogue
  k_wt  <<<dim3(DD2/64, DD1/64, NROW), 256, 0, stream>>>(vsum, wt);
  k_xb  <<<(BATCH*NROW*DD1)/1024, 256, 0, stream>>>(x, xb);
  k_gemm<<<dim3(DD2/128, BATCH/64, NROW), 256, 0, stream>>>(xb, wt, out);
}